// Round 1
// baseline (341.234 us; speedup 1.0000x reference)
//
#include <hip/hip_runtime.h>
#include <stdint.h>

// ---------------------------------------------------------------------------
// NRI-style graph block:
//   K0: convert weights fp32->bf16 into ws (Wo* also split hi/lo for accuracy)
//   K1: edge MLP  (gather pre_msg -> h1 -> h2 -> rel_type-weighted msgs)
//   K2: receiver scatter-sum (edges are receiver-contiguous: recv = e/63)
//   K3: node MLP in split-bf16 (hi+lo, 3-term MFMA ~ fp32 accuracy) + residual
// ---------------------------------------------------------------------------

typedef __attribute__((ext_vector_type(8))) __bf16 bf16x8;
typedef __attribute__((ext_vector_type(4))) float  f32x4;
typedef __attribute__((ext_vector_type(8))) short  short8;

#define MFMA16(a, b, c) __builtin_amdgcn_mfma_f32_16x16x32_bf16((a), (b), (c), 0, 0, 0)

union U64q { unsigned long long u; __bf16 q[4]; };

static __device__ __forceinline__ unsigned short bfb(__bf16 x) {
  union { __bf16 b; unsigned short u; } c; c.b = x; return c.u;
}

// ---- ws layout (bytes) ----
#define WS_W1    0          // [4][256][128] bf16  (262144 B)
#define WS_W2    262144     // [4][64][256] bf16   (131072 B)
#define WS_O1H   393216     // [256][128] bf16 hi  (65536)
#define WS_O1L   458752
#define WS_O2H   524288     // [256][256] bf16 hi  (131072)
#define WS_O2L   655360
#define WS_O3H   786432     // [64][256] bf16 hi   (32768)
#define WS_O3L   819200
#define WS_MSGS  1048576    // [B*E][64] f32       (66060288)
#define WS_AGG   67108864   // [B*N][64] f32       (1048576)
#define WS_NEED  68157440

// ===========================================================================
// K0: weight conversion
// ===========================================================================
__global__ __launch_bounds__(256) void k0_convert(
    const float* __restrict__ W1, const float* __restrict__ W2,
    const float* __restrict__ Wo1, const float* __restrict__ Wo2,
    const float* __restrict__ Wo3, char* __restrict__ ws) {
  int i = blockIdx.x * 256 + threadIdx.x;
  __bf16* w1  = (__bf16*)(ws + WS_W1);
  __bf16* w2  = (__bf16*)(ws + WS_W2);
  __bf16* o1h = (__bf16*)(ws + WS_O1H);
  __bf16* o1l = (__bf16*)(ws + WS_O1L);
  __bf16* o2h = (__bf16*)(ws + WS_O2H);
  __bf16* o2l = (__bf16*)(ws + WS_O2L);
  __bf16* o3h = (__bf16*)(ws + WS_O3H);
  __bf16* o3l = (__bf16*)(ws + WS_O3L);
  if (i < 131072) { w1[i] = (__bf16)W1[i]; return; }
  i -= 131072;
  if (i < 65536) { w2[i] = (__bf16)W2[i]; return; }
  i -= 65536;
  if (i < 32768) { float v = Wo1[i]; __bf16 h = (__bf16)v; o1h[i] = h; o1l[i] = (__bf16)(v - (float)h); return; }
  i -= 32768;
  if (i < 65536) { float v = Wo2[i]; __bf16 h = (__bf16)v; o2h[i] = h; o2l[i] = (__bf16)(v - (float)h); return; }
  i -= 65536;
  if (i < 16384) { float v = Wo3[i]; __bf16 h = (__bf16)v; o3h[i] = h; o3l[i] = (__bf16)(v - (float)h); return; }
}

// ===========================================================================
// K1: edge MLP. One block = 64 edges of one batch. 256 threads (4 waves).
// Transposed GEMMs: mfma(A=W-frag, B=activation-frag) so lane regs are 4
// consecutive output features (ds_write_b64 / float4 stores).
// LDS: pre[64][128]bf16 swz (16K) | h1[64][256]bf16 swz (32K) | wbuf (16K)
// ===========================================================================
__global__ __launch_bounds__(256, 2) void k1_edge(
    const float* __restrict__ inputs, const float* __restrict__ rel_type,
    const float* __restrict__ b1g, const float* __restrict__ b2g,
    const char* __restrict__ wsr, float* __restrict__ msgs) {
  __shared__ char sm[65536];
  char* preS = sm;            // [edge][128] bf16, byte ^= (edge&7)<<4
  char* h1s  = sm + 16384;    // [edge][256] bf16, byte ^= (edge&7)<<4
  char* wbuf = sm + 49152;    // 16KB weight chunk, [kslot][col][16B]

  const char* w1 = wsr + WS_W1;
  const char* w2 = wsr + WS_W2;

  const int tid = threadIdx.x;
  const int bid = blockIdx.x;
  const int b    = bid / 63;
  const int tile = bid - b * 63;
  const int e0   = tile * 64;
  const int l = tid & 63;
  const int w = tid >> 6;
  const int lg = l >> 4;        // lane group 0..3
  const int lr = l & 15;

  // ---- stage pre_msg via gather: [recv feats | send feats] -> bf16 LDS ----
  const float* inpB = inputs + b * 4096;
  for (int it = 0; it < 16; ++it) {
    int u = tid + it * 256;          // 0..4095 ; 64 rows x 64 (2-col units)
    int row = u >> 6;
    int up  = u & 63;
    int e = e0 + row;
    int r = e / 63;
    int j = e - r * 63;
    int s = j + (j >= r ? 1 : 0);
    int col = up * 2;
    int node = (col < 64) ? r : s;
    int f    = (col < 64) ? col : col - 64;
    float2 v = *(const float2*)(inpB + node * 64 + f);
    ushort2 p;
    p.x = bfb((__bf16)v.x);
    p.y = bfb((__bf16)v.y);
    int off = (row * 256 + col * 2) ^ ((row & 7) << 4);
    *(ushort2*)(preS + off) = p;
  }

  // rel_type for the edges this lane epilogues (GEMM2 partition)
  const int wm = w >> 1, wn = w & 1;
  float reltv[2][4];
#pragma unroll
  for (int nfi = 0; nfi < 2; ++nfi) {
    int edge = wn * 32 + nfi * 16 + lr;
    const float* rp = rel_type + ((size_t)(b * 4032 + e0 + edge)) * 4;
#pragma unroll
    for (int kap = 0; kap < 4; ++kap) reltv[nfi][kap] = rp[kap];
  }

  f32x4 macc[2][2] = {};

  for (int kap = 0; kap < 4; ++kap) {
    // ===== GEMM1: h1^T = W1[kap] @ pre^T  (M=256, N=64 edges, K=128) =====
    f32x4 acc1[4][4] = {};
    for (int kq = 0; kq < 4; ++kq) {
      __syncthreads();  // protect wbuf from previous consumers
      // stage W1 chunk: src plain row-major [256][128], k-quarter kq
#pragma unroll
      for (int it = 0; it < 4; ++it) {
        int u = tid + it * 256;            // 0..1023 ; ks=u>>8, col=u&255
        int ks = u >> 8, colc = u & 255;
        short8 vv = *(const short8*)(w1 + (kap * 256 + colc) * 256 + kq * 64 + ks * 16);
        *(short8*)(wbuf + u * 16) = vv;
      }
      __syncthreads();
      bf16x8 af[4], bfg[4];
#pragma unroll
      for (int mfi = 0; mfi < 4; ++mfi) {
        int colp = w * 64 + mfi * 16 + lr;
        af[mfi] = *(const bf16x8*)(wbuf + ((lg * 256 + colp) << 4));
      }
#pragma unroll
      for (int nfi = 0; nfi < 4; ++nfi) {
        int edge = nfi * 16 + lr;
        int off = (edge * 256 + kq * 64 + (lg << 4)) ^ ((edge & 7) << 4);
        bfg[nfi] = *(const bf16x8*)(preS + off);
      }
#pragma unroll
      for (int mfi = 0; mfi < 4; ++mfi)
#pragma unroll
        for (int nfi = 0; nfi < 4; ++nfi)
          acc1[mfi][nfi] = MFMA16(af[mfi], bfg[nfi], acc1[mfi][nfi]);
    }
    // h1 epilogue: +b1, relu, ->bf16, b64 write (4 consecutive h1 cols/lane)
#pragma unroll
    for (int mfi = 0; mfi < 4; ++mfi) {
      int col0 = w * 64 + mfi * 16 + (lg << 2);
      f32x4 bv = *(const f32x4*)(b1g + kap * 256 + col0);
#pragma unroll
      for (int nfi = 0; nfi < 4; ++nfi) {
        int edge = nfi * 16 + lr;
        U64q pk;
#pragma unroll
        for (int i2 = 0; i2 < 4; ++i2)
          pk.q[i2] = (__bf16)fmaxf(acc1[mfi][nfi][i2] + bv[i2], 0.f);
        int off = (edge * 512 + col0 * 2) ^ ((edge & 7) << 4);
        *(unsigned long long*)(h1s + off) = pk.u;
      }
    }
    __syncthreads();  // h1 complete before GEMM2 reads

    // ===== GEMM2: h2^T = W2[kap] @ h1^T  (M=64, N=64 edges, K=256) =====
    f32x4 acc2[2][2] = {};
    for (int h = 0; h < 2; ++h) {
      __syncthreads();  // protect wbuf
#pragma unroll
      for (int it = 0; it < 4; ++it) {
        int u = tid + it * 256;            // ks=u>>6 (0..15), col=u&63
        int ks = u >> 6, colc = u & 63;
        short8 vv = *(const short8*)(w2 + (kap * 64 + colc) * 512 + h * 256 + ks * 16);
        *(short8*)(wbuf + u * 16) = vv;
      }
      __syncthreads();
#pragma unroll
      for (int kk = 0; kk < 4; ++kk) {
        bf16x8 a2[2], bb[2];
#pragma unroll
        for (int mfi = 0; mfi < 2; ++mfi) {
          int colp = wm * 32 + mfi * 16 + lr;
          a2[mfi] = *(const bf16x8*)(wbuf + (((kk * 4 + lg) * 64 + colp) << 4));
        }
#pragma unroll
        for (int nfi = 0; nfi < 2; ++nfi) {
          int edge = wn * 32 + nfi * 16 + lr;
          int k = h * 128 + kk * 32 + (lg << 3);
          int off = (edge * 512 + k * 2) ^ ((edge & 7) << 4);
          bb[nfi] = *(const bf16x8*)(h1s + off);
        }
#pragma unroll
        for (int mfi = 0; mfi < 2; ++mfi)
#pragma unroll
          for (int nfi = 0; nfi < 2; ++nfi)
            acc2[mfi][nfi] = MFMA16(a2[mfi], bb[nfi], acc2[mfi][nfi]);
      }
    }
    // epilogue: macc += relu(acc2 + b2) * rel_type
#pragma unroll
    for (int mfi = 0; mfi < 2; ++mfi) {
      int col0 = wm * 32 + mfi * 16 + (lg << 2);
      f32x4 bv = *(const f32x4*)(b2g + kap * 64 + col0);
#pragma unroll
      for (int nfi = 0; nfi < 2; ++nfi) {
        float rt = reltv[nfi][kap];
#pragma unroll
        for (int i2 = 0; i2 < 4; ++i2)
          macc[mfi][nfi][i2] += fmaxf(acc2[mfi][nfi][i2] + bv[i2], 0.f) * rt;
      }
    }
  }

  // ---- write msgs (float4: 4 consecutive msg features per lane) ----
#pragma unroll
  for (int mfi = 0; mfi < 2; ++mfi) {
    int col0 = wm * 32 + mfi * 16 + (lg << 2);
#pragma unroll
    for (int nfi = 0; nfi < 2; ++nfi) {
      int edge = wn * 32 + nfi * 16 + lr;
      *(f32x4*)(msgs + ((size_t)(b * 4032 + e0 + edge)) * 64 + col0) = macc[mfi][nfi];
    }
  }
}

// ===========================================================================
// K2: receiver scatter-sum. agg[b,n,:] = sum_{j<63} msgs[b, n*63+j, :]
// ===========================================================================
__global__ __launch_bounds__(256) void k2_agg(const float* __restrict__ msgs,
                                              float* __restrict__ agg) {
  int tid = threadIdx.x;
  int m  = tid & 63;
  int rl = tid >> 6;
  int row = blockIdx.x * 4 + rl;     // 0..4095
  int b = row >> 6, n = row & 63;
  const float* src = msgs + ((size_t)(b * 4032 + n * 63)) * 64 + m;
  float s0 = 0.f, s1 = 0.f, s2 = 0.f;
#pragma unroll 7
  for (int j = 0; j < 63; j += 3) {
    s0 += src[j * 64];
    s1 += src[(j + 1) * 64];
    s2 += src[(j + 2) * 64];
  }
  agg[row * 64 + m] = s0 + s1 + s2;
}

// ===========================================================================
// K3: node MLP with split-bf16 (hi+lo) 3-term MFMA (~fp32 accuracy) + residual
// One block = 32 node-rows. 256 threads (4 waves).
// LDS: augHi(8K)|augLo(8K)|h1hi(16K)|h1lo(16K)|h2lo(16K); h2hi reuses aug.
// ===========================================================================
__global__ __launch_bounds__(256) void k3_node(
    const float* __restrict__ inputs, const float* __restrict__ agg,
    const char* __restrict__ wsr,
    const float* __restrict__ bo1, const float* __restrict__ bo2,
    const float* __restrict__ bo3, float* __restrict__ out) {
  __shared__ char sm[65536];
  char* augHi = sm;                  // [32][128] bf16 swz
  char* augLo = sm + 8192;
  char* h1hi  = sm + 16384;          // [32][256] bf16 swz
  char* h1lo  = sm + 32768;
  char* h2hi  = sm;                  // reuse aug region after GEMM1
  char* h2lo  = sm + 49152;

  const char* o1h = wsr + WS_O1H;
  const char* o1l = wsr + WS_O1L;
  const char* o2h = wsr + WS_O2H;
  const char* o2l = wsr + WS_O2L;
  const char* o3h = wsr + WS_O3H;
  const char* o3l = wsr + WS_O3L;

  const int tid = threadIdx.x;
  const int l = tid & 63;
  const int w = tid >> 6;
  const int lg = l >> 4, lr = l & 15;
  const int r0 = blockIdx.x * 32;

  // ---- stage aug = [inputs | agg] as hi/lo bf16 ----
  for (int it = 0; it < 8; ++it) {
    int u = tid + it * 256;          // 0..2047 ; 32 rows x 64 (2-col units)
    int row = u >> 6, up = u & 63;
    int col = up * 2;
    const float* src = (col < 64) ? (inputs + (r0 + row) * 64 + col)
                                  : (agg + (r0 + row) * 64 + (col - 64));
    float2 v = *(const float2*)src;
    __bf16 h0 = (__bf16)v.x, h1v = (__bf16)v.y;
    __bf16 l0 = (__bf16)(v.x - (float)h0), l1 = (__bf16)(v.y - (float)h1v);
    int off = (row * 256 + col * 2) ^ ((row & 7) << 4);
    ushort2 ph; ph.x = bfb(h0); ph.y = bfb(h1v);
    ushort2 pl; pl.x = bfb(l0); pl.y = bfb(l1);
    *(ushort2*)(augHi + off) = ph;
    *(ushort2*)(augLo + off) = pl;
  }
  __syncthreads();

  // ===== GEMM1: h1^T = Wo1 @ aug^T (M=256, N=32, K=128), 3-term split =====
  f32x4 acc[4][2] = {};
#pragma unroll
  for (int kk = 0; kk < 4; ++kk) {
    bf16x8 ah[4], al[4], bh[2], bl[2];
#pragma unroll
    for (int mfi = 0; mfi < 4; ++mfi) {
      int colp = w * 64 + mfi * 16 + lr;
      int gb = colp * 256 + kk * 64 + (lg << 4);
      ah[mfi] = *(const bf16x8*)(o1h + gb);
      al[mfi] = *(const bf16x8*)(o1l + gb);
    }
#pragma unroll
    for (int nfi = 0; nfi < 2; ++nfi) {
      int row = nfi * 16 + lr;
      int off = (row * 256 + kk * 64 + (lg << 4)) ^ ((row & 7) << 4);
      bh[nfi] = *(const bf16x8*)(augHi + off);
      bl[nfi] = *(const bf16x8*)(augLo + off);
    }
#pragma unroll
    for (int mfi = 0; mfi < 4; ++mfi)
#pragma unroll
      for (int nfi = 0; nfi < 2; ++nfi) {
        acc[mfi][nfi] = MFMA16(ah[mfi], bh[nfi], acc[mfi][nfi]);
        acc[mfi][nfi] = MFMA16(ah[mfi], bl[nfi], acc[mfi][nfi]);
        acc[mfi][nfi] = MFMA16(al[mfi], bh[nfi], acc[mfi][nfi]);
      }
  }
#pragma unroll
  for (int mfi = 0; mfi < 4; ++mfi) {
    int col0 = w * 64 + mfi * 16 + (lg << 2);
    f32x4 bv = *(const f32x4*)(bo1 + col0);
#pragma unroll
    for (int nfi = 0; nfi < 2; ++nfi) {
      int row = nfi * 16 + lr;
      U64q ph, pl;
#pragma unroll
      for (int i2 = 0; i2 < 4; ++i2) {
        float x = fmaxf(acc[mfi][nfi][i2] + bv[i2], 0.f);
        ph.q[i2] = (__bf16)x;
        pl.q[i2] = (__bf16)(x - (float)ph.q[i2]);
      }
      int off = (row * 512 + col0 * 2) ^ ((row & 7) << 4);
      *(unsigned long long*)(h1hi + off) = ph.u;
      *(unsigned long long*)(h1lo + off) = pl.u;
    }
  }
  __syncthreads();

  // ===== GEMM2: h2^T = Wo2 @ h1^T (M=256, N=32, K=256) =====
  f32x4 acc2[4][2] = {};
#pragma unroll
  for (int kk = 0; kk < 8; ++kk) {
    bf16x8 ah[4], al[4], bh[2], bl[2];
#pragma unroll
    for (int mfi = 0; mfi < 4; ++mfi) {
      int colp = w * 64 + mfi * 16 + lr;
      int gb = colp * 512 + kk * 64 + (lg << 4);
      ah[mfi] = *(const bf16x8*)(o2h + gb);
      al[mfi] = *(const bf16x8*)(o2l + gb);
    }
#pragma unroll
    for (int nfi = 0; nfi < 2; ++nfi) {
      int row = nfi * 16 + lr;
      int off = (row * 512 + kk * 64 + (lg << 4)) ^ ((row & 7) << 4);
      bh[nfi] = *(const bf16x8*)(h1hi + off);
      bl[nfi] = *(const bf16x8*)(h1lo + off);
    }
#pragma unroll
    for (int mfi = 0; mfi < 4; ++mfi)
#pragma unroll
      for (int nfi = 0; nfi < 2; ++nfi) {
        acc2[mfi][nfi] = MFMA16(ah[mfi], bh[nfi], acc2[mfi][nfi]);
        acc2[mfi][nfi] = MFMA16(ah[mfi], bl[nfi], acc2[mfi][nfi]);
        acc2[mfi][nfi] = MFMA16(al[mfi], bh[nfi], acc2[mfi][nfi]);
      }
  }
#pragma unroll
  for (int mfi = 0; mfi < 4; ++mfi) {
    int col0 = w * 64 + mfi * 16 + (lg << 2);
    f32x4 bv = *(const f32x4*)(bo2 + col0);
#pragma unroll
    for (int nfi = 0; nfi < 2; ++nfi) {
      int row = nfi * 16 + lr;
      U64q ph, pl;
#pragma unroll
      for (int i2 = 0; i2 < 4; ++i2) {
        float x = fmaxf(acc2[mfi][nfi][i2] + bv[i2], 0.f);
        ph.q[i2] = (__bf16)x;
        pl.q[i2] = (__bf16)(x - (float)ph.q[i2]);
      }
      int off = (row * 512 + col0 * 2) ^ ((row & 7) << 4);
      *(unsigned long long*)(h2hi + off) = ph.u;
      *(unsigned long long*)(h2lo + off) = pl.u;
    }
  }
  __syncthreads();

  // ===== GEMM3: pred^T = Wo3 @ h2^T (M=64, N=32, K=256) + residual =====
  f32x4 acc3[2] = {};
#pragma unroll
  for (int kk = 0; kk < 8; ++kk) {
    int colp = w * 16 + lr;
    int gb = colp * 512 + kk * 64 + (lg << 4);
    bf16x8 a3h = *(const bf16x8*)(o3h + gb);
    bf16x8 a3l = *(const bf16x8*)(o3l + gb);
#pragma unroll
    for (int nfi = 0; nfi < 2; ++nfi) {
      int row = nfi * 16 + lr;
      int off = (row * 512 + kk * 64 + (lg << 4)) ^ ((row & 7) << 4);
      bf16x8 b3h = *(const bf16x8*)(h2hi + off);
      bf16x8 b3l = *(const bf16x8*)(h2lo + off);
      acc3[nfi] = MFMA16(a3h, b3h, acc3[nfi]);
      acc3[nfi] = MFMA16(a3h, b3l, acc3[nfi]);
      acc3[nfi] = MFMA16(a3l, b3h, acc3[nfi]);
    }
  }
#pragma unroll
  for (int nfi = 0; nfi < 2; ++nfi) {
    int row = nfi * 16 + lr;
    int col0 = w * 16 + (lg << 2);
    f32x4 bv = *(const f32x4*)(bo3 + col0);
    f32x4 iv = *(const f32x4*)(inputs + (r0 + row) * 64 + col0);
    f32x4 o;
#pragma unroll
    for (int i2 = 0; i2 < 4; ++i2) o[i2] = acc3[nfi][i2] + bv[i2] + iv[i2];
    *(f32x4*)(out + (r0 + row) * 64 + col0) = o;
  }
}

// ===========================================================================
extern "C" void kernel_launch(void* const* d_in, const int* in_sizes, int n_in,
                              void* d_out, int out_size, void* d_ws, size_t ws_size,
                              hipStream_t stream) {
  (void)in_sizes; (void)n_in; (void)out_size;
  if (ws_size < (size_t)WS_NEED) return;  // need ~68.2 MB scratch

  const float* inputs   = (const float*)d_in[0];
  const float* rel_type = (const float*)d_in[1];
  const float* W1  = (const float*)d_in[4];
  const float* b1  = (const float*)d_in[5];
  const float* W2  = (const float*)d_in[6];
  const float* b2  = (const float*)d_in[7];
  const float* Wo1 = (const float*)d_in[8];
  const float* bo1 = (const float*)d_in[9];
  const float* Wo2 = (const float*)d_in[10];
  const float* bo2 = (const float*)d_in[11];
  const float* Wo3 = (const float*)d_in[12];
  const float* bo3 = (const float*)d_in[13];

  char* ws = (char*)d_ws;
  float* msgs = (float*)(ws + WS_MSGS);
  float* agg  = (float*)(ws + WS_AGG);
  float* out  = (float*)d_out;

  k0_convert<<<dim3(1216), dim3(256), 0, stream>>>(W1, W2, Wo1, Wo2, Wo3, ws);
  k1_edge<<<dim3(4032), dim3(256), 0, stream>>>(inputs, rel_type, b1, b2, ws, msgs);
  k2_agg<<<dim3(1024), dim3(256), 0, stream>>>(msgs, agg);
  k3_node<<<dim3(128), dim3(256), 0, stream>>>(inputs, agg, ws, bo1, bo2, bo3, out);
}

// Round 2
// 313.694 us; speedup vs baseline: 1.0878x; 1.0878x over previous
//
#include <hip/hip_runtime.h>
#include <stdint.h>

// ---------------------------------------------------------------------------
// NRI-style graph block:
//   K0: convert weights fp32->bf16 into ws (Wo* also split hi/lo for accuracy)
//   K1: edge MLP, v2: 128-edge-slot tiles (64 edges x 2 batches), weights
//       direct L2->reg (no LDS weight staging), h1 in two halves (64KB LDS,
//       2 blocks/CU). 17 barriers/block vs 52 in v1.
//   K2: receiver scatter-sum (edges are receiver-contiguous: recv = e/63)
//   K3: node MLP in split-bf16 (hi+lo, 3-term MFMA ~ fp32 accuracy) + residual
// ---------------------------------------------------------------------------

typedef __attribute__((ext_vector_type(8))) __bf16 bf16x8;
typedef __attribute__((ext_vector_type(4))) float  f32x4;
typedef __attribute__((ext_vector_type(8))) short  short8;

#define MFMA16(a, b, c) __builtin_amdgcn_mfma_f32_16x16x32_bf16((a), (b), (c), 0, 0, 0)

union U64q { unsigned long long u; __bf16 q[4]; };

static __device__ __forceinline__ unsigned short bfb(__bf16 x) {
  union { __bf16 b; unsigned short u; } c; c.b = x; return c.u;
}

// ---- ws layout (bytes) ----
#define WS_W1    0          // [4][256][128] bf16  (262144 B)
#define WS_W2    262144     // [4][64][256] bf16   (131072 B)
#define WS_O1H   393216     // [256][128] bf16 hi  (65536)
#define WS_O1L   458752
#define WS_O2H   524288     // [256][256] bf16 hi  (131072)
#define WS_O2L   655360
#define WS_O3H   786432     // [64][256] bf16 hi   (32768)
#define WS_O3L   819200
#define WS_MSGS  1048576    // [B*E][64] f32       (66060288)
#define WS_AGG   67108864   // [B*N][64] f32       (1048576)
#define WS_NEED  68157440

// ===========================================================================
// K0: weight conversion
// ===========================================================================
__global__ __launch_bounds__(256) void k0_convert(
    const float* __restrict__ W1, const float* __restrict__ W2,
    const float* __restrict__ Wo1, const float* __restrict__ Wo2,
    const float* __restrict__ Wo3, char* __restrict__ ws) {
  int i = blockIdx.x * 256 + threadIdx.x;
  __bf16* w1  = (__bf16*)(ws + WS_W1);
  __bf16* w2  = (__bf16*)(ws + WS_W2);
  __bf16* o1h = (__bf16*)(ws + WS_O1H);
  __bf16* o1l = (__bf16*)(ws + WS_O1L);
  __bf16* o2h = (__bf16*)(ws + WS_O2H);
  __bf16* o2l = (__bf16*)(ws + WS_O2L);
  __bf16* o3h = (__bf16*)(ws + WS_O3H);
  __bf16* o3l = (__bf16*)(ws + WS_O3L);
  if (i < 131072) { w1[i] = (__bf16)W1[i]; return; }
  i -= 131072;
  if (i < 65536) { w2[i] = (__bf16)W2[i]; return; }
  i -= 65536;
  if (i < 32768) { float v = Wo1[i]; __bf16 h = (__bf16)v; o1h[i] = h; o1l[i] = (__bf16)(v - (float)h); return; }
  i -= 32768;
  if (i < 65536) { float v = Wo2[i]; __bf16 h = (__bf16)v; o2h[i] = h; o2l[i] = (__bf16)(v - (float)h); return; }
  i -= 65536;
  if (i < 16384) { float v = Wo3[i]; __bf16 h = (__bf16)v; o3h[i] = h; o3l[i] = (__bf16)(v - (float)h); return; }
}

// ===========================================================================
// K1 v2: edge MLP. One block = 64 edges x 2 batches (128 N-slots), 512 thr.
// Weights: direct global->reg fragments (L2-resident, 4-lane 64B groups).
// LDS: preS [128][128]bf16 swz (32K) | h1half [128][128]bf16 swz (32K).
// GEMM1 h1 computed in two 128-col halves; GEMM2 accumulates across halves.
// ===========================================================================
__global__ __launch_bounds__(512, 4) void k1_edge(
    const float* __restrict__ inputs, const float* __restrict__ rel_type,
    const float* __restrict__ b1g, const float* __restrict__ b2g,
    const char* __restrict__ wsr, float* __restrict__ msgs) {
  __shared__ char sm[65536];
  char* preS = sm;           // [slot 0..127][256B] bf16, byte ^= (slot&7)<<4
  char* h1s  = sm + 32768;   // [slot 0..127][256B] bf16 (one h1-col half), swz

  const char* w1 = wsr + WS_W1;
  const char* w2 = wsr + WS_W2;

  const int tid = threadIdx.x;
  const int bid = blockIdx.x;
  const int tile = bid % 63;
  const int c    = bid / 63;       // batch pair index 0..31
  const int e0 = tile * 64;
  const int b0 = c * 2;
  const int l = tid & 63, w = tid >> 6;
  const int lg = l >> 4, lr = l & 15;

  // ---- stage pre_msg: slot = bb*64 + (edge-e0); [recv | send] feats ----
#pragma unroll
  for (int it = 0; it < 16; ++it) {
    int u = tid + it * 512;        // 0..8191 : 128 slots x 64 float2-units
    int row = u >> 6, up = u & 63;
    int col = up * 2;
    int bb = row >> 6;
    int e = e0 + (row & 63);
    int r = e / 63;
    int j = e - r * 63;
    int s = j + (j >= r ? 1 : 0);
    int node = (col < 64) ? r : s;
    int f = col & 63;
    float2 v = *(const float2*)(inputs + ((size_t)(b0 + bb)) * 4096 + node * 64 + f);
    ushort2 p;
    p.x = bfb((__bf16)v.x);
    p.y = bfb((__bf16)v.y);
    int off = (row * 256 + col * 2) ^ ((row & 7) << 4);
    *(ushort2*)(preS + off) = p;
  }
  __syncthreads();

  // GEMM2 wave partition: wm = out-feature quarter, wn = batch-of-pair
  const int wm = w >> 1;           // 0..3 -> out features wm*16..+15
  const int wn = w & 1;            // 0..1 -> slots wn*64..+63 (batch b0+wn)

  f32x4 macc[4] = {};              // [nfi] : final msgs accumulator

  for (int kap = 0; kap < 4; ++kap) {
    f32x4 acc2[4] = {};            // [nfi] : h2 pre-activation, accum over halves
    for (int half = 0; half < 2; ++half) {
      // ===== GEMM1 half: h1 cols [half*128, +128), 16 cols per wave =====
      f32x4 acc1[8] = {};
      const int colp = half * 128 + w * 16 + lr;
      bf16x8 af[4];
#pragma unroll
      for (int kq = 0; kq < 4; ++kq)
        af[kq] = *(const bf16x8*)(w1 + (((size_t)(kap * 256 + colp)) << 8) + kq * 64 + (lg << 4));
#pragma unroll
      for (int kq = 0; kq < 4; ++kq) {
        bf16x8 bfg[8];
#pragma unroll
        for (int nfi = 0; nfi < 8; ++nfi) {
          int off = ((nfi * 16 + lr) * 256 + kq * 64 + (lg << 4)) ^ ((lr & 7) << 4);
          bfg[nfi] = *(const bf16x8*)(preS + off);
        }
#pragma unroll
        for (int nfi = 0; nfi < 8; ++nfi)
          acc1[nfi] = MFMA16(af[kq], bfg[nfi], acc1[nfi]);
      }
      // h1 epilogue: +b1, relu, bf16, b64 write (4 consecutive cols/lane)
      {
        int col0 = half * 128 + w * 16 + (lg << 2);
        f32x4 bv = *(const f32x4*)(b1g + kap * 256 + col0);
        int cb = (w * 16 + (lg << 2)) * 2;   // local col byte
#pragma unroll
        for (int nfi = 0; nfi < 8; ++nfi) {
          int slot = nfi * 16 + lr;
          U64q pk;
#pragma unroll
          for (int i2 = 0; i2 < 4; ++i2)
            pk.q[i2] = (__bf16)fmaxf(acc1[nfi][i2] + bv[i2], 0.f);
          int off = (slot * 256 + cb) ^ ((lr & 7) << 4);
          *(unsigned long long*)(h1s + off) = pk.u;
        }
      }
      __syncthreads();   // h1 half ready

      // ===== GEMM2 partial: k window [half*128, +128) =====
#pragma unroll
      for (int kk = 0; kk < 4; ++kk) {
        bf16x8 a2 = *(const bf16x8*)(w2 + (((size_t)(kap * 64 + wm * 16 + lr)) << 9)
                                     + (half * 4 + kk) * 64 + (lg << 4));
        bf16x8 bb2[4];
#pragma unroll
        for (int nfi = 0; nfi < 4; ++nfi) {
          int slot = wn * 64 + nfi * 16 + lr;
          int off = (slot * 256 + kk * 64 + (lg << 4)) ^ ((lr & 7) << 4);
          bb2[nfi] = *(const bf16x8*)(h1s + off);
        }
#pragma unroll
        for (int nfi = 0; nfi < 4; ++nfi)
          acc2[nfi] = MFMA16(a2, bb2[nfi], acc2[nfi]);
      }
      __syncthreads();   // GEMM2 reads done before next half overwrites h1s
    }
    // ---- epilogue: macc += relu(acc2 + b2) * rel_type[kap] ----
    {
      int col0 = wm * 16 + (lg << 2);
      f32x4 bv = *(const f32x4*)(b2g + kap * 64 + col0);
#pragma unroll
      for (int nfi = 0; nfi < 4; ++nfi) {
        int e = e0 + nfi * 16 + lr;
        float rt = rel_type[(((size_t)(b0 + wn)) * 4032 + e) * 4 + kap];
#pragma unroll
        for (int i2 = 0; i2 < 4; ++i2)
          macc[nfi][i2] += fmaxf(acc2[nfi][i2] + bv[i2], 0.f) * rt;
      }
    }
  }

  // ---- write msgs (float4: 4 consecutive msg features per lane) ----
  {
    int col0 = wm * 16 + (lg << 2);
#pragma unroll
    for (int nfi = 0; nfi < 4; ++nfi) {
      int e = e0 + nfi * 16 + lr;
      *(f32x4*)(msgs + (((size_t)(b0 + wn)) * 4032 + e) * 64 + col0) = macc[nfi];
    }
  }
}

// ===========================================================================
// K2: receiver scatter-sum. agg[b,n,:] = sum_{j<63} msgs[b, n*63+j, :]
// ===========================================================================
__global__ __launch_bounds__(256) void k2_agg(const float* __restrict__ msgs,
                                              float* __restrict__ agg) {
  int tid = threadIdx.x;
  int m  = tid & 63;
  int rl = tid >> 6;
  int row = blockIdx.x * 4 + rl;     // 0..4095
  int b = row >> 6, n = row & 63;
  const float* src = msgs + ((size_t)(b * 4032 + n * 63)) * 64 + m;
  float s0 = 0.f, s1 = 0.f, s2 = 0.f;
#pragma unroll 7
  for (int j = 0; j < 63; j += 3) {
    s0 += src[j * 64];
    s1 += src[(j + 1) * 64];
    s2 += src[(j + 2) * 64];
  }
  agg[row * 64 + m] = s0 + s1 + s2;
}

// ===========================================================================
// K3: node MLP with split-bf16 (hi+lo) 3-term MFMA (~fp32 accuracy) + residual
// One block = 32 node-rows. 256 threads (4 waves).
// ===========================================================================
__global__ __launch_bounds__(256) void k3_node(
    const float* __restrict__ inputs, const float* __restrict__ agg,
    const char* __restrict__ wsr,
    const float* __restrict__ bo1, const float* __restrict__ bo2,
    const float* __restrict__ bo3, float* __restrict__ out) {
  __shared__ char sm[65536];
  char* augHi = sm;                  // [32][128] bf16 swz
  char* augLo = sm + 8192;
  char* h1hi  = sm + 16384;          // [32][256] bf16 swz
  char* h1lo  = sm + 32768;
  char* h2hi  = sm;                  // reuse aug region after GEMM1
  char* h2lo  = sm + 49152;

  const char* o1h = wsr + WS_O1H;
  const char* o1l = wsr + WS_O1L;
  const char* o2h = wsr + WS_O2H;
  const char* o2l = wsr + WS_O2L;
  const char* o3h = wsr + WS_O3H;
  const char* o3l = wsr + WS_O3L;

  const int tid = threadIdx.x;
  const int l = tid & 63;
  const int w = tid >> 6;
  const int lg = l >> 4, lr = l & 15;
  const int r0 = blockIdx.x * 32;

  // ---- stage aug = [inputs | agg] as hi/lo bf16 ----
  for (int it = 0; it < 8; ++it) {
    int u = tid + it * 256;          // 0..2047 ; 32 rows x 64 (2-col units)
    int row = u >> 6, up = u & 63;
    int col = up * 2;
    const float* src = (col < 64) ? (inputs + (r0 + row) * 64 + col)
                                  : (agg + (r0 + row) * 64 + (col - 64));
    float2 v = *(const float2*)src;
    __bf16 h0 = (__bf16)v.x, h1v = (__bf16)v.y;
    __bf16 l0 = (__bf16)(v.x - (float)h0), l1 = (__bf16)(v.y - (float)h1v);
    int off = (row * 256 + col * 2) ^ ((row & 7) << 4);
    ushort2 ph; ph.x = bfb(h0); ph.y = bfb(h1v);
    ushort2 pl; pl.x = bfb(l0); pl.y = bfb(l1);
    *(ushort2*)(augHi + off) = ph;
    *(ushort2*)(augLo + off) = pl;
  }
  __syncthreads();

  // ===== GEMM1: h1^T = Wo1 @ aug^T (M=256, N=32, K=128), 3-term split =====
  f32x4 acc[4][2] = {};
#pragma unroll
  for (int kk = 0; kk < 4; ++kk) {
    bf16x8 ah[4], al[4], bh[2], bl[2];
#pragma unroll
    for (int mfi = 0; mfi < 4; ++mfi) {
      int colp = w * 64 + mfi * 16 + lr;
      int gb = colp * 256 + kk * 64 + (lg << 4);
      ah[mfi] = *(const bf16x8*)(o1h + gb);
      al[mfi] = *(const bf16x8*)(o1l + gb);
    }
#pragma unroll
    for (int nfi = 0; nfi < 2; ++nfi) {
      int row = nfi * 16 + lr;
      int off = (row * 256 + kk * 64 + (lg << 4)) ^ ((row & 7) << 4);
      bh[nfi] = *(const bf16x8*)(augHi + off);
      bl[nfi] = *(const bf16x8*)(augLo + off);
    }
#pragma unroll
    for (int mfi = 0; mfi < 4; ++mfi)
#pragma unroll
      for (int nfi = 0; nfi < 2; ++nfi) {
        acc[mfi][nfi] = MFMA16(ah[mfi], bh[nfi], acc[mfi][nfi]);
        acc[mfi][nfi] = MFMA16(ah[mfi], bl[nfi], acc[mfi][nfi]);
        acc[mfi][nfi] = MFMA16(al[mfi], bh[nfi], acc[mfi][nfi]);
      }
  }
#pragma unroll
  for (int mfi = 0; mfi < 4; ++mfi) {
    int col0 = w * 64 + mfi * 16 + (lg << 2);
    f32x4 bv = *(const f32x4*)(bo1 + col0);
#pragma unroll
    for (int nfi = 0; nfi < 2; ++nfi) {
      int row = nfi * 16 + lr;
      U64q ph, pl;
#pragma unroll
      for (int i2 = 0; i2 < 4; ++i2) {
        float x = fmaxf(acc[mfi][nfi][i2] + bv[i2], 0.f);
        ph.q[i2] = (__bf16)x;
        pl.q[i2] = (__bf16)(x - (float)ph.q[i2]);
      }
      int off = (row * 512 + col0 * 2) ^ ((row & 7) << 4);
      *(unsigned long long*)(h1hi + off) = ph.u;
      *(unsigned long long*)(h1lo + off) = pl.u;
    }
  }
  __syncthreads();

  // ===== GEMM2: h2^T = Wo2 @ h1^T (M=256, N=32, K=256) =====
  f32x4 acc2[4][2] = {};
#pragma unroll
  for (int kk = 0; kk < 8; ++kk) {
    bf16x8 ah[4], al[4], bh[2], bl[2];
#pragma unroll
    for (int mfi = 0; mfi < 4; ++mfi) {
      int colp = w * 64 + mfi * 16 + lr;
      int gb = colp * 512 + kk * 64 + (lg << 4);
      ah[mfi] = *(const bf16x8*)(o2h + gb);
      al[mfi] = *(const bf16x8*)(o2l + gb);
    }
#pragma unroll
    for (int nfi = 0; nfi < 2; ++nfi) {
      int row = nfi * 16 + lr;
      int off = (row * 512 + kk * 64 + (lg << 4)) ^ ((row & 7) << 4);
      bh[nfi] = *(const bf16x8*)(h1hi + off);
      bl[nfi] = *(const bf16x8*)(h1lo + off);
    }
#pragma unroll
    for (int mfi = 0; mfi < 4; ++mfi)
#pragma unroll
      for (int nfi = 0; nfi < 2; ++nfi) {
        acc2[mfi][nfi] = MFMA16(ah[mfi], bh[nfi], acc2[mfi][nfi]);
        acc2[mfi][nfi] = MFMA16(ah[mfi], bl[nfi], acc2[mfi][nfi]);
        acc2[mfi][nfi] = MFMA16(al[mfi], bh[nfi], acc2[mfi][nfi]);
      }
  }
#pragma unroll
  for (int mfi = 0; mfi < 4; ++mfi) {
    int col0 = w * 64 + mfi * 16 + (lg << 2);
    f32x4 bv = *(const f32x4*)(bo2 + col0);
#pragma unroll
    for (int nfi = 0; nfi < 2; ++nfi) {
      int row = nfi * 16 + lr;
      U64q ph, pl;
#pragma unroll
      for (int i2 = 0; i2 < 4; ++i2) {
        float x = fmaxf(acc2[mfi][nfi][i2] + bv[i2], 0.f);
        ph.q[i2] = (__bf16)x;
        pl.q[i2] = (__bf16)(x - (float)ph.q[i2]);
      }
      int off = (row * 512 + col0 * 2) ^ ((row & 7) << 4);
      *(unsigned long long*)(h2hi + off) = ph.u;
      *(unsigned long long*)(h2lo + off) = pl.u;
    }
  }
  __syncthreads();

  // ===== GEMM3: pred^T = Wo3 @ h2^T (M=64, N=32, K=256) + residual =====
  f32x4 acc3[2] = {};
#pragma unroll
  for (int kk = 0; kk < 8; ++kk) {
    int colp = w * 16 + lr;
    int gb = colp * 512 + kk * 64 + (lg << 4);
    bf16x8 a3h = *(const bf16x8*)(o3h + gb);
    bf16x8 a3l = *(const bf16x8*)(o3l + gb);
#pragma unroll
    for (int nfi = 0; nfi < 2; ++nfi) {
      int row = nfi * 16 + lr;
      int off = (row * 512 + kk * 64 + (lg << 4)) ^ ((row & 7) << 4);
      bf16x8 b3h = *(const bf16x8*)(h2hi + off);
      bf16x8 b3l = *(const bf16x8*)(h2lo + off);
      acc3[nfi] = MFMA16(a3h, b3h, acc3[nfi]);
      acc3[nfi] = MFMA16(a3h, b3l, acc3[nfi]);
      acc3[nfi] = MFMA16(a3l, b3h, acc3[nfi]);
    }
  }
#pragma unroll
  for (int nfi = 0; nfi < 2; ++nfi) {
    int row = nfi * 16 + lr;
    int col0 = w * 16 + (lg << 2);
    f32x4 bv = *(const f32x4*)(bo3 + col0);
    f32x4 iv = *(const f32x4*)(inputs + (r0 + row) * 64 + col0);
    f32x4 o;
#pragma unroll
    for (int i2 = 0; i2 < 4; ++i2) o[i2] = acc3[nfi][i2] + bv[i2] + iv[i2];
    *(f32x4*)(out + (r0 + row) * 64 + col0) = o;
  }
}

// ===========================================================================
extern "C" void kernel_launch(void* const* d_in, const int* in_sizes, int n_in,
                              void* d_out, int out_size, void* d_ws, size_t ws_size,
                              hipStream_t stream) {
  (void)in_sizes; (void)n_in; (void)out_size;
  if (ws_size < (size_t)WS_NEED) return;  // need ~68.2 MB scratch

  const float* inputs   = (const float*)d_in[0];
  const float* rel_type = (const float*)d_in[1];
  const float* W1  = (const float*)d_in[4];
  const float* b1  = (const float*)d_in[5];
  const float* W2  = (const float*)d_in[6];
  const float* b2  = (const float*)d_in[7];
  const float* Wo1 = (const float*)d_in[8];
  const float* bo1 = (const float*)d_in[9];
  const float* Wo2 = (const float*)d_in[10];
  const float* bo2 = (const float*)d_in[11];
  const float* Wo3 = (const float*)d_in[12];
  const float* bo3 = (const float*)d_in[13];

  char* ws = (char*)d_ws;
  float* msgs = (float*)(ws + WS_MSGS);
  float* agg  = (float*)(ws + WS_AGG);
  float* out  = (float*)d_out;

  k0_convert<<<dim3(1216), dim3(256), 0, stream>>>(W1, W2, Wo1, Wo2, Wo3, ws);
  k1_edge<<<dim3(2016), dim3(512), 0, stream>>>(inputs, rel_type, b1, b2, ws, msgs);
  k2_agg<<<dim3(1024), dim3(256), 0, stream>>>(msgs, agg);
  k3_node<<<dim3(128), dim3(256), 0, stream>>>(inputs, agg, ws, bo1, bo2, bo3, out);
}

// Round 3
// 264.360 us; speedup vs baseline: 1.2908x; 1.1866x over previous
//
#include <hip/hip_runtime.h>
#include <stdint.h>

// ---------------------------------------------------------------------------
// NRI-style graph block:
//   K0: convert weights fp32->bf16 into ws (Wo* also split hi/lo for accuracy)
//   K1: edge MLP v3: 128-slot tiles (64 edges x 2 batches), weights direct
//       L2->reg, h1 in two halves. launch_bounds(512,2): R2's (512,4) acted
//       as 4 blocks/CU -> 64-VGPR cap -> ~600MB scratch spill traffic.
//   K2: receiver scatter-sum (edges are receiver-contiguous: recv = e/63)
//   K3: node MLP in split-bf16 (hi+lo, 3-term MFMA ~ fp32 accuracy) + residual
// ---------------------------------------------------------------------------

typedef __attribute__((ext_vector_type(8))) __bf16 bf16x8;
typedef __attribute__((ext_vector_type(4))) float  f32x4;
typedef __attribute__((ext_vector_type(8))) short  short8;

#define MFMA16(a, b, c) __builtin_amdgcn_mfma_f32_16x16x32_bf16((a), (b), (c), 0, 0, 0)

union U64q { unsigned long long u; __bf16 q[4]; };

static __device__ __forceinline__ unsigned short bfb(__bf16 x) {
  union { __bf16 b; unsigned short u; } c; c.b = x; return c.u;
}

// ---- ws layout (bytes) ----
#define WS_W1    0          // [4][256][128] bf16  (262144 B)
#define WS_W2    262144     // [4][64][256] bf16   (131072 B)
#define WS_O1H   393216     // [256][128] bf16 hi  (65536)
#define WS_O1L   458752
#define WS_O2H   524288     // [256][256] bf16 hi  (131072)
#define WS_O2L   655360
#define WS_O3H   786432     // [64][256] bf16 hi   (32768)
#define WS_O3L   819200
#define WS_MSGS  1048576    // [B*E][64] f32       (66060288)
#define WS_AGG   67108864   // [B*N][64] f32       (1048576)
#define WS_NEED  68157440

// ===========================================================================
// K0: weight conversion
// ===========================================================================
__global__ __launch_bounds__(256) void k0_convert(
    const float* __restrict__ W1, const float* __restrict__ W2,
    const float* __restrict__ Wo1, const float* __restrict__ Wo2,
    const float* __restrict__ Wo3, char* __restrict__ ws) {
  int i = blockIdx.x * 256 + threadIdx.x;
  __bf16* w1  = (__bf16*)(ws + WS_W1);
  __bf16* w2  = (__bf16*)(ws + WS_W2);
  __bf16* o1h = (__bf16*)(ws + WS_O1H);
  __bf16* o1l = (__bf16*)(ws + WS_O1L);
  __bf16* o2h = (__bf16*)(ws + WS_O2H);
  __bf16* o2l = (__bf16*)(ws + WS_O2L);
  __bf16* o3h = (__bf16*)(ws + WS_O3H);
  __bf16* o3l = (__bf16*)(ws + WS_O3L);
  if (i < 131072) { w1[i] = (__bf16)W1[i]; return; }
  i -= 131072;
  if (i < 65536) { w2[i] = (__bf16)W2[i]; return; }
  i -= 65536;
  if (i < 32768) { float v = Wo1[i]; __bf16 h = (__bf16)v; o1h[i] = h; o1l[i] = (__bf16)(v - (float)h); return; }
  i -= 32768;
  if (i < 65536) { float v = Wo2[i]; __bf16 h = (__bf16)v; o2h[i] = h; o2l[i] = (__bf16)(v - (float)h); return; }
  i -= 65536;
  if (i < 16384) { float v = Wo3[i]; __bf16 h = (__bf16)v; o3h[i] = h; o3l[i] = (__bf16)(v - (float)h); return; }
}

// ===========================================================================
// K1 v3: edge MLP. One block = 64 edges x 2 batches (128 N-slots), 512 thr.
// Weights: direct global->reg fragments (L2-resident, 4-lane 64B groups).
// LDS: preS [128][128]bf16 swz (32K) | h1half [128][128]bf16 swz (32K).
// launch_bounds(512,2): 2 blocks/CU -> 128-VGPR cap (no spill; R2 lesson).
// ===========================================================================
__global__ __launch_bounds__(512, 2) void k1_edge(
    const float* __restrict__ inputs, const float* __restrict__ rel_type,
    const float* __restrict__ b1g, const float* __restrict__ b2g,
    const char* __restrict__ wsr, float* __restrict__ msgs) {
  __shared__ char sm[65536];
  char* preS = sm;           // [slot 0..127][256B] bf16, byte ^= (slot&7)<<4
  char* h1s  = sm + 32768;   // [slot 0..127][256B] bf16 (one h1-col half), swz

  const char* w1 = wsr + WS_W1;
  const char* w2 = wsr + WS_W2;

  const int tid = threadIdx.x;
  const int bid = blockIdx.x;
  const int tile = bid % 63;
  const int c    = bid / 63;       // batch pair index 0..31
  const int e0 = tile * 64;
  const int b0 = c * 2;
  const int l = tid & 63, w = tid >> 6;
  const int lg = l >> 4, lr = l & 15;

  // ---- stage pre_msg: slot = bb*64 + (edge-e0); [recv | send] feats ----
#pragma unroll
  for (int it = 0; it < 16; ++it) {
    int u = tid + it * 512;        // 0..8191 : 128 slots x 64 float2-units
    int row = u >> 6, up = u & 63;
    int col = up * 2;
    int bb = row >> 6;
    int e = e0 + (row & 63);
    int r = e / 63;
    int j = e - r * 63;
    int s = j + (j >= r ? 1 : 0);
    int node = (col < 64) ? r : s;
    int f = col & 63;
    float2 v = *(const float2*)(inputs + ((size_t)(b0 + bb)) * 4096 + node * 64 + f);
    ushort2 p;
    p.x = bfb((__bf16)v.x);
    p.y = bfb((__bf16)v.y);
    int off = (row * 256 + col * 2) ^ ((row & 7) << 4);
    *(ushort2*)(preS + off) = p;
  }
  __syncthreads();

  // GEMM2 wave partition: wm = out-feature quarter, wn = batch-of-pair
  const int wm = w >> 1;           // 0..3 -> out features wm*16..+15
  const int wn = w & 1;            // 0..1 -> slots wn*64..+63 (batch b0+wn)

  f32x4 macc[4] = {};              // [nfi] : final msgs accumulator

  for (int kap = 0; kap < 4; ++kap) {
    f32x4 acc2[4] = {};            // [nfi] : h2 pre-activation, accum over halves
    for (int half = 0; half < 2; ++half) {
      // ===== GEMM1 half: h1 cols [half*128, +128), 16 cols per wave =====
      f32x4 acc1[8] = {};
      const int colp = half * 128 + w * 16 + lr;
      const char* w1c = w1 + (((size_t)(kap * 256 + colp)) << 8) + (lg << 4);
#pragma unroll
      for (int kq = 0; kq < 4; ++kq) {
        // A-fragment loaded per-kq (not hoisted) to bound live registers
        bf16x8 af = *(const bf16x8*)(w1c + kq * 64);
#pragma unroll
        for (int nfi = 0; nfi < 8; ++nfi) {
          int off = ((nfi * 16 + lr) * 256 + kq * 64 + (lg << 4)) ^ ((lr & 7) << 4);
          bf16x8 bfg = *(const bf16x8*)(preS + off);
          acc1[nfi] = MFMA16(af, bfg, acc1[nfi]);
        }
      }
      // h1 epilogue: +b1, relu, bf16, b64 write (4 consecutive cols/lane)
      {
        int col0 = half * 128 + w * 16 + (lg << 2);
        f32x4 bv = *(const f32x4*)(b1g + kap * 256 + col0);
        int cb = (w * 16 + (lg << 2)) * 2;   // local col byte
#pragma unroll
        for (int nfi = 0; nfi < 8; ++nfi) {
          int slot = nfi * 16 + lr;
          U64q pk;
#pragma unroll
          for (int i2 = 0; i2 < 4; ++i2)
            pk.q[i2] = (__bf16)fmaxf(acc1[nfi][i2] + bv[i2], 0.f);
          int off = (slot * 256 + cb) ^ ((lr & 7) << 4);
          *(unsigned long long*)(h1s + off) = pk.u;
        }
      }
      __syncthreads();   // h1 half ready

      // ===== GEMM2 partial: k window [half*128, +128) =====
      const char* w2c = w2 + (((size_t)(kap * 64 + wm * 16 + lr)) << 9)
                        + half * 256 + (lg << 4);
#pragma unroll
      for (int kk = 0; kk < 4; ++kk) {
        bf16x8 a2 = *(const bf16x8*)(w2c + kk * 64);
#pragma unroll
        for (int nfi = 0; nfi < 4; ++nfi) {
          int slot = wn * 64 + nfi * 16 + lr;
          int off = (slot * 256 + kk * 64 + (lg << 4)) ^ ((lr & 7) << 4);
          bf16x8 bb2 = *(const bf16x8*)(h1s + off);
          acc2[nfi] = MFMA16(a2, bb2, acc2[nfi]);
        }
      }
      __syncthreads();   // GEMM2 reads done before next half overwrites h1s
    }
    // ---- epilogue: macc += relu(acc2 + b2) * rel_type[kap] ----
    {
      int col0 = wm * 16 + (lg << 2);
      f32x4 bv = *(const f32x4*)(b2g + kap * 64 + col0);
#pragma unroll
      for (int nfi = 0; nfi < 4; ++nfi) {
        int e = e0 + nfi * 16 + lr;
        float rt = rel_type[(((size_t)(b0 + wn)) * 4032 + e) * 4 + kap];
#pragma unroll
        for (int i2 = 0; i2 < 4; ++i2)
          macc[nfi][i2] += fmaxf(acc2[nfi][i2] + bv[i2], 0.f) * rt;
      }
    }
  }

  // ---- write msgs (float4: 4 consecutive msg features per lane) ----
  {
    int col0 = wm * 16 + (lg << 2);
#pragma unroll
    for (int nfi = 0; nfi < 4; ++nfi) {
      int e = e0 + nfi * 16 + lr;
      *(f32x4*)(msgs + (((size_t)(b0 + wn)) * 4032 + e) * 64 + col0) = macc[nfi];
    }
  }
}

// ===========================================================================
// K2: receiver scatter-sum. agg[b,n,:] = sum_{j<63} msgs[b, n*63+j, :]
// ===========================================================================
__global__ __launch_bounds__(256) void k2_agg(const float* __restrict__ msgs,
                                              float* __restrict__ agg) {
  int tid = threadIdx.x;
  int m  = tid & 63;
  int rl = tid >> 6;
  int row = blockIdx.x * 4 + rl;     // 0..4095
  int b = row >> 6, n = row & 63;
  const float* src = msgs + ((size_t)(b * 4032 + n * 63)) * 64 + m;
  float s0 = 0.f, s1 = 0.f, s2 = 0.f;
#pragma unroll 7
  for (int j = 0; j < 63; j += 3) {
    s0 += src[j * 64];
    s1 += src[(j + 1) * 64];
    s2 += src[(j + 2) * 64];
  }
  agg[row * 64 + m] = s0 + s1 + s2;
}

// ===========================================================================
// K3: node MLP with split-bf16 (hi+lo) 3-term MFMA (~fp32 accuracy) + residual
// One block = 32 node-rows. 256 threads (4 waves).
// ===========================================================================
__global__ __launch_bounds__(256) void k3_node(
    const float* __restrict__ inputs, const float* __restrict__ agg,
    const char* __restrict__ wsr,
    const float* __restrict__ bo1, const float* __restrict__ bo2,
    const float* __restrict__ bo3, float* __restrict__ out) {
  __shared__ char sm[65536];
  char* augHi = sm;                  // [32][128] bf16 swz
  char* augLo = sm + 8192;
  char* h1hi  = sm + 16384;          // [32][256] bf16 swz
  char* h1lo  = sm + 32768;
  char* h2hi  = sm;                  // reuse aug region after GEMM1
  char* h2lo  = sm + 49152;

  const char* o1h = wsr + WS_O1H;
  const char* o1l = wsr + WS_O1L;
  const char* o2h = wsr + WS_O2H;
  const char* o2l = wsr + WS_O2L;
  const char* o3h = wsr + WS_O3H;
  const char* o3l = wsr + WS_O3L;

  const int tid = threadIdx.x;
  const int l = tid & 63;
  const int w = tid >> 6;
  const int lg = l >> 4, lr = l & 15;
  const int r0 = blockIdx.x * 32;

  // ---- stage aug = [inputs | agg] as hi/lo bf16 ----
  for (int it = 0; it < 8; ++it) {
    int u = tid + it * 256;          // 0..2047 ; 32 rows x 64 (2-col units)
    int row = u >> 6, up = u & 63;
    int col = up * 2;
    const float* src = (col < 64) ? (inputs + (r0 + row) * 64 + col)
                                  : (agg + (r0 + row) * 64 + (col - 64));
    float2 v = *(const float2*)src;
    __bf16 h0 = (__bf16)v.x, h1v = (__bf16)v.y;
    __bf16 l0 = (__bf16)(v.x - (float)h0), l1 = (__bf16)(v.y - (float)h1v);
    int off = (row * 256 + col * 2) ^ ((row & 7) << 4);
    ushort2 ph; ph.x = bfb(h0); ph.y = bfb(h1v);
    ushort2 pl; pl.x = bfb(l0); pl.y = bfb(l1);
    *(ushort2*)(augHi + off) = ph;
    *(ushort2*)(augLo + off) = pl;
  }
  __syncthreads();

  // ===== GEMM1: h1^T = Wo1 @ aug^T (M=256, N=32, K=128), 3-term split =====
  f32x4 acc[4][2] = {};
#pragma unroll
  for (int kk = 0; kk < 4; ++kk) {
    bf16x8 ah[4], al[4], bh[2], bl[2];
#pragma unroll
    for (int mfi = 0; mfi < 4; ++mfi) {
      int colp = w * 64 + mfi * 16 + lr;
      int gb = colp * 256 + kk * 64 + (lg << 4);
      ah[mfi] = *(const bf16x8*)(o1h + gb);
      al[mfi] = *(const bf16x8*)(o1l + gb);
    }
#pragma unroll
    for (int nfi = 0; nfi < 2; ++nfi) {
      int row = nfi * 16 + lr;
      int off = (row * 256 + kk * 64 + (lg << 4)) ^ ((row & 7) << 4);
      bh[nfi] = *(const bf16x8*)(augHi + off);
      bl[nfi] = *(const bf16x8*)(augLo + off);
    }
#pragma unroll
    for (int mfi = 0; mfi < 4; ++mfi)
#pragma unroll
      for (int nfi = 0; nfi < 2; ++nfi) {
        acc[mfi][nfi] = MFMA16(ah[mfi], bh[nfi], acc[mfi][nfi]);
        acc[mfi][nfi] = MFMA16(ah[mfi], bl[nfi], acc[mfi][nfi]);
        acc[mfi][nfi] = MFMA16(al[mfi], bh[nfi], acc[mfi][nfi]);
      }
  }
#pragma unroll
  for (int mfi = 0; mfi < 4; ++mfi) {
    int col0 = w * 64 + mfi * 16 + (lg << 2);
    f32x4 bv = *(const f32x4*)(bo1 + col0);
#pragma unroll
    for (int nfi = 0; nfi < 2; ++nfi) {
      int row = nfi * 16 + lr;
      U64q ph, pl;
#pragma unroll
      for (int i2 = 0; i2 < 4; ++i2) {
        float x = fmaxf(acc[mfi][nfi][i2] + bv[i2], 0.f);
        ph.q[i2] = (__bf16)x;
        pl.q[i2] = (__bf16)(x - (float)ph.q[i2]);
      }
      int off = (row * 512 + col0 * 2) ^ ((row & 7) << 4);
      *(unsigned long long*)(h1hi + off) = ph.u;
      *(unsigned long long*)(h1lo + off) = pl.u;
    }
  }
  __syncthreads();

  // ===== GEMM2: h2^T = Wo2 @ h1^T (M=256, N=32, K=256) =====
  f32x4 acc2[4][2] = {};
#pragma unroll
  for (int kk = 0; kk < 8; ++kk) {
    bf16x8 ah[4], al[4], bh[2], bl[2];
#pragma unroll
    for (int mfi = 0; mfi < 4; ++mfi) {
      int colp = w * 64 + mfi * 16 + lr;
      int gb = colp * 512 + kk * 64 + (lg << 4);
      ah[mfi] = *(const bf16x8*)(o2h + gb);
      al[mfi] = *(const bf16x8*)(o2l + gb);
    }
#pragma unroll
    for (int nfi = 0; nfi < 2; ++nfi) {
      int row = nfi * 16 + lr;
      int off = (row * 512 + kk * 64 + (lg << 4)) ^ ((row & 7) << 4);
      bh[nfi] = *(const bf16x8*)(h1hi + off);
      bl[nfi] = *(const bf16x8*)(h1lo + off);
    }
#pragma unroll
    for (int mfi = 0; mfi < 4; ++mfi)
#pragma unroll
      for (int nfi = 0; nfi < 2; ++nfi) {
        acc2[mfi][nfi] = MFMA16(ah[mfi], bh[nfi], acc2[mfi][nfi]);
        acc2[mfi][nfi] = MFMA16(ah[mfi], bl[nfi], acc2[mfi][nfi]);
        acc2[mfi][nfi] = MFMA16(al[mfi], bh[nfi], acc2[mfi][nfi]);
      }
  }
#pragma unroll
  for (int mfi = 0; mfi < 4; ++mfi) {
    int col0 = w * 64 + mfi * 16 + (lg << 2);
    f32x4 bv = *(const f32x4*)(bo2 + col0);
#pragma unroll
    for (int nfi = 0; nfi < 2; ++nfi) {
      int row = nfi * 16 + lr;
      U64q ph, pl;
#pragma unroll
      for (int i2 = 0; i2 < 4; ++i2) {
        float x = fmaxf(acc2[mfi][nfi][i2] + bv[i2], 0.f);
        ph.q[i2] = (__bf16)x;
        pl.q[i2] = (__bf16)(x - (float)ph.q[i2]);
      }
      int off = (row * 512 + col0 * 2) ^ ((row & 7) << 4);
      *(unsigned long long*)(h2hi + off) = ph.u;
      *(unsigned long long*)(h2lo + off) = pl.u;
    }
  }
  __syncthreads();

  // ===== GEMM3: pred^T = Wo3 @ h2^T (M=64, N=32, K=256) + residual =====
  f32x4 acc3[2] = {};
#pragma unroll
  for (int kk = 0; kk < 8; ++kk) {
    int colp = w * 16 + lr;
    int gb = colp * 512 + kk * 64 + (lg << 4);
    bf16x8 a3h = *(const bf16x8*)(o3h + gb);
    bf16x8 a3l = *(const bf16x8*)(o3l + gb);
#pragma unroll
    for (int nfi = 0; nfi < 2; ++nfi) {
      int row = nfi * 16 + lr;
      int off = (row * 512 + kk * 64 + (lg << 4)) ^ ((row & 7) << 4);
      bf16x8 b3h = *(const bf16x8*)(h2hi + off);
      bf16x8 b3l = *(const bf16x8*)(h2lo + off);
      acc3[nfi] = MFMA16(a3h, b3h, acc3[nfi]);
      acc3[nfi] = MFMA16(a3h, b3l, acc3[nfi]);
      acc3[nfi] = MFMA16(a3l, b3h, acc3[nfi]);
    }
  }
#pragma unroll
  for (int nfi = 0; nfi < 2; ++nfi) {
    int row = nfi * 16 + lr;
    int col0 = w * 16 + (lg << 2);
    f32x4 bv = *(const f32x4*)(bo3 + col0);
    f32x4 iv = *(const f32x4*)(inputs + (r0 + row) * 64 + col0);
    f32x4 o;
#pragma unroll
    for (int i2 = 0; i2 < 4; ++i2) o[i2] = acc3[nfi][i2] + bv[i2] + iv[i2];
    *(f32x4*)(out + (r0 + row) * 64 + col0) = o;
  }
}

// ===========================================================================
extern "C" void kernel_launch(void* const* d_in, const int* in_sizes, int n_in,
                              void* d_out, int out_size, void* d_ws, size_t ws_size,
                              hipStream_t stream) {
  (void)in_sizes; (void)n_in; (void)out_size;
  if (ws_size < (size_t)WS_NEED) return;  // need ~68.2 MB scratch

  const float* inputs   = (const float*)d_in[0];
  const float* rel_type = (const float*)d_in[1];
  const float* W1  = (const float*)d_in[4];
  const float* b1  = (const float*)d_in[5];
  const float* W2  = (const float*)d_in[6];
  const float* b2  = (const float*)d_in[7];
  const float* Wo1 = (const float*)d_in[8];
  const float* bo1 = (const float*)d_in[9];
  const float* Wo2 = (const float*)d_in[10];
  const float* bo2 = (const float*)d_in[11];
  const float* Wo3 = (const float*)d_in[12];
  const float* bo3 = (const float*)d_in[13];

  char* ws = (char*)d_ws;
  float* msgs = (float*)(ws + WS_MSGS);
  float* agg  = (float*)(ws + WS_AGG);
  float* out  = (float*)d_out;

  k0_convert<<<dim3(1216), dim3(256), 0, stream>>>(W1, W2, Wo1, Wo2, Wo3, ws);
  k1_edge<<<dim3(2016), dim3(512), 0, stream>>>(inputs, rel_type, b1, b2, ws, msgs);
  k2_agg<<<dim3(1024), dim3(256), 0, stream>>>(msgs, agg);
  k3_node<<<dim3(128), dim3(256), 0, stream>>>(inputs, agg, ws, bo1, bo2, bo3, out);
}